// Round 2
// baseline (434.191 us; speedup 1.0000x reference)
//
#include <hip/hip_runtime.h>
#include <stdint.h>

// ---------------------------------------------------------------------------
// DkNN round 6: revert to the proven round-4 structure (128x128 tile, 4 waves,
// 4 blocks/CU, XCD swizzle, gload_lds staging) with ONE change:
//   MFMA shape 16x16x32 -> 32x32x16 (rate 2382 vs 2075 TF, half the MFMA
//   instruction count per K-step, identical ds_read count & LDS layout).
// Fragment layouts: A/B row|col = lane&31, k = (lane>>5)*8 + e (2xK analog of
// the HW-verified 16x16x32 layout); C/D col=lane&31,
// row=(reg&3)+8*(reg>>2)+4*(lane>>5) (verified m74/m101).
// prep_all / classify unchanged.
// ---------------------------------------------------------------------------

typedef __attribute__((ext_vector_type(8))) short short8;     // 8 bf16 = 4 VGPR
typedef __attribute__((ext_vector_type(16))) float float16v;  // 32x32 C/D

static __device__ __forceinline__ unsigned short bf16_rn(float f) {
    unsigned int u = __float_as_uint(f);
    unsigned int r = (u + 0x7FFFu + ((u >> 16) & 1u)) >> 16;
    return (unsigned short)r;
}

static __device__ __forceinline__ void gload_lds16(const void* g, void* l) {
    __builtin_amdgcn_global_load_lds(
        (const __attribute__((address_space(1))) unsigned int*)g,
        (__attribute__((address_space(3))) unsigned int*)l, 16, 0, 0);
}

// Fused prep: blocks [0, Np/4) convert train rows (4/block); blocks
// [Np/4, Np/4+Mp) prep one query row each (normalize, center, hi/lo, q2, gkey).
__global__ void prep_all(const float* __restrict__ X, const float* __restrict__ x,
                         const float* __restrict__ center,
                         unsigned short* __restrict__ Bh, unsigned short* __restrict__ Bl,
                         float* __restrict__ xn2,
                         unsigned short* __restrict__ Ah, unsigned short* __restrict__ Al,
                         float* __restrict__ q2, unsigned long long* __restrict__ gkey,
                         int nb_train, int Np, int B, int Mp) {
    const int tid = threadIdx.x;
    const int tb = Np >> 2;
    if (blockIdx.x < (unsigned)tb) {
        // ---- train side: 4 rows per block, one wave each ----
        int row = blockIdx.x * 4 + (tid >> 6);
        int lane = tid & 63;
        if (row >= nb_train) {
            ushort4 z = make_ushort4(0, 0, 0, 0);
            *(ushort4*)(Bh + (size_t)row * 256 + lane * 4) = z;
            *(ushort4*)(Bl + (size_t)row * 256 + lane * 4) = z;
            if (lane == 0) xn2[row] = 3.0e38f;
            return;
        }
        float4 v = ((const float4*)(X + (size_t)row * 256))[lane];
        ushort4 h, l;
        h.x = bf16_rn(v.x); l.x = bf16_rn(v.x - __uint_as_float((unsigned)h.x << 16));
        h.y = bf16_rn(v.y); l.y = bf16_rn(v.y - __uint_as_float((unsigned)h.y << 16));
        h.z = bf16_rn(v.z); l.z = bf16_rn(v.z - __uint_as_float((unsigned)h.z << 16));
        h.w = bf16_rn(v.w); l.w = bf16_rn(v.w - __uint_as_float((unsigned)h.w << 16));
        *(ushort4*)(Bh + (size_t)row * 256 + lane * 4) = h;
        *(ushort4*)(Bl + (size_t)row * 256 + lane * 4) = l;
        float ss = v.x * v.x + v.y * v.y + v.z * v.z + v.w * v.w;
        #pragma unroll
        for (int s = 1; s < 64; s <<= 1) ss += __shfl_xor(ss, s);
        if (lane == 0) xn2[row] = ss;
        return;
    }
    // ---- query side: one row per block, 256 threads (d=256) ----
    int row = blockIdx.x - tb;
    if (row >= Mp) return;
    if (tid == 0) gkey[row] = ~0ULL;
    if (row >= B) {
        Ah[(size_t)row * 256 + tid] = 0;
        Al[(size_t)row * 256 + tid] = 0;
        if (tid == 0) q2[row] = 0.0f;
        return;
    }
    float v = x[(size_t)row * 256 + tid];
    float ss = v * v;
    #pragma unroll
    for (int s = 1; s < 64; s <<= 1) ss += __shfl_xor(ss, s);
    __shared__ float partial[4];
    __shared__ float partial2[4];
    if ((tid & 63) == 0) partial[tid >> 6] = ss;
    __syncthreads();
    float tot = partial[0] + partial[1] + partial[2] + partial[3];
    float inv = 1.0f / sqrtf(tot);
    float val = v * inv - center[tid];
    unsigned short hb = bf16_rn(val);
    float hf = __uint_as_float((unsigned int)hb << 16);
    unsigned short lb = bf16_rn(val - hf);
    Ah[(size_t)row * 256 + tid] = hb;
    Al[(size_t)row * 256 + tid] = lb;
    float ss2 = val * val;
    #pragma unroll
    for (int s = 1; s < 64; s <<= 1) ss2 += __shfl_xor(ss2, s);
    if ((tid & 63) == 0) partial2[tid >> 6] = ss2;
    __syncthreads();
    if (tid == 0) q2[row] = partial2[0] + partial2[1] + partial2[2] + partial2[3];
}

// 128x128 tile, 4 waves each computing a 64x64 quadrant (2x2 frags of 32x32).
// K-loop: 12 steps of BK=64, phases 0: Ah.Bh, 1: Al.Bh, 2: Ah.Bl.
// 1D grid, XCD-swizzled: xcd = bid&7 owns n-tile slice; m iterates fastest.
__global__ __launch_bounds__(256, 4) void mfma_tile(
    const unsigned short* __restrict__ Adata,  // [Ah | Al], each Mp*256
    const unsigned short* __restrict__ Bdata,  // [Bh | Bl], each Np*256
    const float* __restrict__ q2, const float* __restrict__ xn2,
    unsigned long long* __restrict__ gkey,
    int Mp, int Np, int nb_train, int B,
    int ntiles, int nper, int mtiles)
{
    __shared__ unsigned short As[128 * 64];   // [row][chunk ^ (row&7)] 16B chunks
    __shared__ unsigned short Bs[128 * 64];
    __shared__ unsigned long long skey[128];

    const int bid = blockIdx.x;
    const int xcd = bid & 7;
    const int s_  = bid >> 3;
    const int n_t = xcd * nper + (s_ / mtiles);
    const int m_t = s_ - (s_ / mtiles) * mtiles;
    if (n_t >= ntiles) return;
    const int mtile = m_t * 128;
    const int ntile = n_t * 128;

    const int tid  = threadIdx.x;
    const int wave = tid >> 6;
    const int lane = tid & 63;

    if (tid < 128) skey[tid] = ~0ULL;

    // ---- staging role: waves 0,1 stage A rows [0:64),[64:128); waves 2,3 for B
    const int isB   = wave >> 1;
    const int Rwave = (wave & 1) * 64;
    const int lrow8  = lane >> 3;   // row within 8-row segment
    const int lchunk = lane & 7;    // LDS chunk slot
    const size_t APROD = (size_t)Mp * 256;
    const size_t BPROD = (size_t)Np * 256;
    const unsigned short* sbase = isB
        ? (Bdata + (size_t)(ntile + Rwave + lrow8) * 256 + (size_t)((lchunk ^ lrow8) * 8))
        : (Adata + (size_t)(mtile + Rwave + lrow8) * 256 + (size_t)((lchunk ^ lrow8) * 8));
    unsigned short* lwave = (isB ? Bs : As) + Rwave * 64;

    // ---- compute role: quadrant (2x2 frags of 32x32)
    const int mq = (wave >> 1) * 64;
    const int nq = (wave & 1) * 64;
    const int l31   = lane & 31;
    const int khalf = lane >> 5;    // k-block of 8 within K=16
    const int sw    = lane & 7;     // LDS chunk swizzle key (row&7 == lane&7)

    float16v acc[2][2];
    #pragma unroll
    for (int i = 0; i < 2; ++i)
        #pragma unroll
        for (int j = 0; j < 2; ++j)
            #pragma unroll
            for (int e = 0; e < 16; ++e)
                acc[i][j][e] = 0.0f;

    for (int s = 0; s < 12; ++s) {
        const int phase = s >> 2;
        const int sk = (s & 3) * 64;
        size_t srcOff = (size_t)sk;
        if (!isB) { if (phase == 1) srcOff += APROD; }   // Al in phase 1
        else      { if (phase == 2) srcOff += BPROD; }   // Bl in phase 2
        const unsigned short* g = sbase + srcOff;
        __syncthreads();   // previous step's compute done before overwrite
        #pragma unroll
        for (int q = 0; q < 8; ++q)
            gload_lds16(g + q * 2048, lwave + q * 512);
        __syncthreads();   // staging complete (vmcnt drain + barrier)
        #pragma unroll
        for (int ks = 0; ks < 4; ++ks) {
            const int wch = ((ks * 2 + khalf) ^ sw) * 8;   // k = ks*16 + khalf*8
            short8 a0 = *(const short8*)&As[(mq +      l31) * 64 + wch];
            short8 a1 = *(const short8*)&As[(mq + 32 + l31) * 64 + wch];
            short8 b0 = *(const short8*)&Bs[(nq +      l31) * 64 + wch];
            short8 b1 = *(const short8*)&Bs[(nq + 32 + l31) * 64 + wch];
            acc[0][0] = __builtin_amdgcn_mfma_f32_32x32x16_bf16(a0, b0, acc[0][0], 0, 0, 0);
            acc[0][1] = __builtin_amdgcn_mfma_f32_32x32x16_bf16(a0, b1, acc[0][1], 0, 0, 0);
            acc[1][0] = __builtin_amdgcn_mfma_f32_32x32x16_bf16(a1, b0, acc[1][0], 0, 0, 0);
            acc[1][1] = __builtin_amdgcn_mfma_f32_32x32x16_bf16(a1, b1, acc[1][1], 0, 0, 0);
        }
    }

    // ---- epilogue: score = q2[m] - 2*dot + xn2[t]; packed argmin ----
    // C/D map: col = lane&31, row = (reg&3) + 8*(reg>>2) + 4*khalf
    float xnv[2];
    #pragma unroll
    for (int j = 0; j < 2; ++j)
        xnv[j] = xn2[ntile + nq + j * 32 + l31];   // pads hold 3e38

    #pragma unroll
    for (int i = 0; i < 2; ++i) {
        #pragma unroll
        for (int reg = 0; reg < 16; ++reg) {
            const int row = (reg & 3) + 8 * (reg >> 2) + 4 * khalf;
            const int lm = mq + i * 32 + row;     // block-local query
            const int gm = mtile + lm;
            unsigned long long best = ~0ULL;
            if (gm < B) {
                float q2v = q2[gm];
                #pragma unroll
                for (int j = 0; j < 2; ++j) {
                    int t_ = ntile + nq + j * 32 + l31;
                    float sc = fmaxf(q2v - 2.0f * acc[i][j][reg] + xnv[j], 0.0f);
                    unsigned long long key =
                        ((unsigned long long)__float_as_uint(sc) << 32) | (unsigned int)t_;
                    best = (key < best) ? key : best;
                }
            }
            #pragma unroll
            for (int sft = 1; sft < 32; sft <<= 1) {
                unsigned long long o = __shfl_xor(best, sft);
                best = (o < best) ? o : best;
            }
            if (l31 == 0 && gm < B) atomicMin(&skey[lm], best);
        }
    }
    __syncthreads();
    if (tid < 128) {
        int mi = mtile + tid;
        if (mi < B && skey[tid] != ~0ULL) atomicMin(gkey + mi, skey[tid]);
    }
}

// One wave per query: 75 gathers across lanes, ballot bincount, bisect p-values.
__global__ void classify(const unsigned long long* __restrict__ gkey,
                         const int* __restrict__ labels,
                         const int* __restrict__ nbr,
                         const int* __restrict__ cali,
                         float* __restrict__ out,
                         int knm1, int nb_cali, int B)
{
    int q = blockIdx.x * 4 + (threadIdx.x >> 6);
    int lane = threadIdx.x & 63;
    if (q >= B) return;
    int closest = (int)(gkey[q] & 0xFFFFFFFFULL);
    int K = knm1 + 1;   // 75
    int lbl0 = -1, lbl1 = -1;
    if (lane < K) {
        int idx = (lane == 0) ? closest : nbr[(size_t)closest * knm1 + (lane - 1)];
        lbl0 = labels[idx];
    }
    int j2 = lane + 64;
    if (j2 < K) {
        int idx = nbr[(size_t)closest * knm1 + (j2 - 1)];
        lbl1 = labels[idx];
    }
    int bestc = 0, bestp = -1;
    #pragma unroll
    for (int c = 0; c < 10; ++c) {
        int cnt = __popcll(__ballot(lbl0 == c)) + __popcll(__ballot(lbl1 == c));
        int v = K - cnt;
        int lo = 0, hi = nb_cali;
        while (lo < hi) {                 // bisect_left
            int mid = (lo + hi) >> 1;
            if (cali[mid] < v) lo = mid + 1; else hi = mid;
        }
        int p = nb_cali - lo;
        if (p > bestp) { bestp = p; bestc = c; }   // strict > == first-occurrence argmax
    }
    float pv = (float)bestp / (float)nb_cali;
    if (lane < 10)
        out[(size_t)q * 10 + lane] = (lane == bestc) ? pv : 0.0f;
}

extern "C" void kernel_launch(void* const* d_in, const int* in_sizes, int n_in,
                              void* d_out, int out_size, void* d_ws, size_t ws_size,
                              hipStream_t stream) {
    const float* x      = (const float*)d_in[0];
    const float* X      = (const float*)d_in[1];
    const float* center = (const float*)d_in[2];
    const int* labels   = (const int*)d_in[3];
    const int* nbr      = (const int*)d_in[4];
    const int* cali     = (const int*)d_in[5];
    float* out = (float*)d_out;

    const int d        = in_sizes[2];              // 256
    const int B        = in_sizes[0] / d;          // 1024
    const int nb_train = in_sizes[3];              // 100000
    const int knm1     = in_sizes[4] / nb_train;   // 74
    const int nb_cali  = in_sizes[5];              // 1000

    const int Mp = (B + 127) & ~127;               // 1024
    const int Np = (nb_train + 127) & ~127;        // 100096

    char* ws = (char*)d_ws;
    size_t off = 0;
    unsigned long long* gkey = (unsigned long long*)(ws + off); off += (size_t)Mp * 8;
    unsigned short* Adata = (unsigned short*)(ws + off); off += (size_t)Mp * 256 * 2 * 2;
    float* q2 = (float*)(ws + off); off += (size_t)Mp * 4;
    unsigned short* Bdata = (unsigned short*)(ws + off); off += (size_t)Np * 256 * 2 * 2;
    float* xn2 = (float*)(ws + off); off += (size_t)Np * 4;

    unsigned short* Ah = Adata;
    unsigned short* Al = Adata + (size_t)Mp * 256;
    unsigned short* Bh = Bdata;
    unsigned short* Bl = Bdata + (size_t)Np * 256;

    prep_all<<<Np / 4 + Mp, 256, 0, stream>>>(X, x, center, Bh, Bl, xn2,
                                              Ah, Al, q2, gkey,
                                              nb_train, Np, B, Mp);
    const int ntiles = Np / 128;                   // 782
    const int mtiles = Mp / 128;                   // 8
    const int nper   = (ntiles + 7) / 8;           // 98
    mfma_tile<<<8 * nper * mtiles, 256, 0, stream>>>(
        Adata, Bdata, q2, xn2, gkey, Mp, Np, nb_train, B, ntiles, nper, mtiles);
    classify<<<(B + 3) / 4, 256, 0, stream>>>(gkey, labels, nbr, cali, out,
                                              knm1, nb_cali, B);
}

// Round 3
// 384.411 us; speedup vs baseline: 1.1295x; 1.1295x over previous
//
#include <hip/hip_runtime.h>
#include <stdint.h>

// ---------------------------------------------------------------------------
// DkNN round 7: revert mfma_tile to the proven round-4 kernel (202 us, zero
// bank conflicts, 4 blocks/CU). One experiment: prep_all restructured from
// 26048 tiny blocks to 1024 fat grid-stride train blocks + 1024 query blocks
// (identical math/traffic, 12.7x fewer dispatched blocks) to split
// "fixed harness overhead" from "prep is genuinely slow" in the ~175 us
// non-GEMM residual.
// ---------------------------------------------------------------------------

typedef __attribute__((ext_vector_type(8))) short short8;   // 8 bf16 = 4 VGPR
typedef __attribute__((ext_vector_type(4))) float float4v;  // MFMA C/D

static __device__ __forceinline__ unsigned short bf16_rn(float f) {
    unsigned int u = __float_as_uint(f);
    unsigned int r = (u + 0x7FFFu + ((u >> 16) & 1u)) >> 16;
    return (unsigned short)r;
}

static __device__ __forceinline__ void gload_lds16(const void* g, void* l) {
    __builtin_amdgcn_global_load_lds(
        (const __attribute__((address_space(1))) unsigned int*)g,
        (__attribute__((address_space(3))) unsigned int*)l, 16, 0, 0);
}

// Fused prep: blocks [0, TRAIN_BLOCKS) grid-stride over train row-quads
// (1 row/wave/iter); blocks [TRAIN_BLOCKS, TRAIN_BLOCKS+Mp) prep one query
// row each (normalize, center, hi/lo, q2, gkey).
__global__ void prep_all(const float* __restrict__ X, const float* __restrict__ x,
                         const float* __restrict__ center,
                         unsigned short* __restrict__ Bh, unsigned short* __restrict__ Bl,
                         float* __restrict__ xn2,
                         unsigned short* __restrict__ Ah, unsigned short* __restrict__ Al,
                         float* __restrict__ q2, unsigned long long* __restrict__ gkey,
                         int nb_train, int Np, int B, int Mp, int train_blocks) {
    const int tid = threadIdx.x;
    if (blockIdx.x < (unsigned)train_blocks) {
        // ---- train side: grid-stride over row-quads, 1 row per wave ----
        const int lane = tid & 63;
        const int wv   = tid >> 6;
        const int nquads = Np >> 2;
        for (int quad = blockIdx.x; quad < nquads; quad += train_blocks) {
            const int row = quad * 4 + wv;
            if (row >= nb_train) {
                ushort4 z = make_ushort4(0, 0, 0, 0);
                *(ushort4*)(Bh + (size_t)row * 256 + lane * 4) = z;
                *(ushort4*)(Bl + (size_t)row * 256 + lane * 4) = z;
                if (lane == 0) xn2[row] = 3.0e38f;
            } else {
                float4 v = ((const float4*)(X + (size_t)row * 256))[lane];
                ushort4 h, l;
                h.x = bf16_rn(v.x); l.x = bf16_rn(v.x - __uint_as_float((unsigned)h.x << 16));
                h.y = bf16_rn(v.y); l.y = bf16_rn(v.y - __uint_as_float((unsigned)h.y << 16));
                h.z = bf16_rn(v.z); l.z = bf16_rn(v.z - __uint_as_float((unsigned)h.z << 16));
                h.w = bf16_rn(v.w); l.w = bf16_rn(v.w - __uint_as_float((unsigned)h.w << 16));
                *(ushort4*)(Bh + (size_t)row * 256 + lane * 4) = h;
                *(ushort4*)(Bl + (size_t)row * 256 + lane * 4) = l;
                float ss = v.x * v.x + v.y * v.y + v.z * v.z + v.w * v.w;
                #pragma unroll
                for (int s = 1; s < 64; s <<= 1) ss += __shfl_xor(ss, s);
                if (lane == 0) xn2[row] = ss;
            }
        }
        return;
    }
    // ---- query side: one row per block, 256 threads (d=256) ----
    int row = blockIdx.x - train_blocks;
    if (row >= Mp) return;
    if (tid == 0) gkey[row] = ~0ULL;
    if (row >= B) {
        Ah[(size_t)row * 256 + tid] = 0;
        Al[(size_t)row * 256 + tid] = 0;
        if (tid == 0) q2[row] = 0.0f;
        return;
    }
    float v = x[(size_t)row * 256 + tid];
    float ss = v * v;
    #pragma unroll
    for (int s = 1; s < 64; s <<= 1) ss += __shfl_xor(ss, s);
    __shared__ float partial[4];
    __shared__ float partial2[4];
    if ((tid & 63) == 0) partial[tid >> 6] = ss;
    __syncthreads();
    float tot = partial[0] + partial[1] + partial[2] + partial[3];
    float inv = 1.0f / sqrtf(tot);
    float val = v * inv - center[tid];
    unsigned short hb = bf16_rn(val);
    float hf = __uint_as_float((unsigned int)hb << 16);
    unsigned short lb = bf16_rn(val - hf);
    Ah[(size_t)row * 256 + tid] = hb;
    Al[(size_t)row * 256 + tid] = lb;
    float ss2 = val * val;
    #pragma unroll
    for (int s = 1; s < 64; s <<= 1) ss2 += __shfl_xor(ss2, s);
    if ((tid & 63) == 0) partial2[tid >> 6] = ss2;
    __syncthreads();
    if (tid == 0) q2[row] = partial2[0] + partial2[1] + partial2[2] + partial2[3];
}

// 128x128 tile, 4 waves each computing a 64x64 quadrant (4x4 frags of 16x16x32).
// K-loop: 12 steps of BK=64, phases 0: Ah.Bh, 1: Al.Bh, 2: Ah.Bl.
// 1D grid, XCD-swizzled: xcd = bid&7 owns n-tile slice [xcd*nper, ...); within
// the slice m iterates fastest so same-n blocks run back-to-back on one XCD.
__global__ __launch_bounds__(256, 4) void mfma_tile(
    const unsigned short* __restrict__ Adata,  // [Ah | Al], each Mp*256
    const unsigned short* __restrict__ Bdata,  // [Bh | Bl], each Np*256
    const float* __restrict__ q2, const float* __restrict__ xn2,
    unsigned long long* __restrict__ gkey,
    int Mp, int Np, int nb_train, int B,
    int ntiles, int nper, int mtiles)
{
    __shared__ unsigned short As[128 * 64];   // [row][chunk ^ (row&7)] 16B chunks
    __shared__ unsigned short Bs[128 * 64];
    __shared__ unsigned long long skey[128];

    const int bid = blockIdx.x;
    const int xcd = bid & 7;
    const int s_  = bid >> 3;
    const int n_t = xcd * nper + (s_ / mtiles);
    const int m_t = s_ - (s_ / mtiles) * mtiles;
    if (n_t >= ntiles) return;
    const int mtile = m_t * 128;
    const int ntile = n_t * 128;

    const int tid  = threadIdx.x;
    const int wave = tid >> 6;
    const int lane = tid & 63;

    if (tid < 128) skey[tid] = ~0ULL;

    // ---- staging role: waves 0,1 stage A rows [0:64),[64:128); waves 2,3 for B
    const int isB   = wave >> 1;
    const int Rwave = (wave & 1) * 64;
    const int lrow8  = lane >> 3;   // row within 8-row segment
    const int lchunk = lane & 7;    // LDS chunk slot
    const size_t APROD = (size_t)Mp * 256;
    const size_t BPROD = (size_t)Np * 256;
    const unsigned short* sbase = isB
        ? (Bdata + (size_t)(ntile + Rwave + lrow8) * 256 + (size_t)((lchunk ^ lrow8) * 8))
        : (Adata + (size_t)(mtile + Rwave + lrow8) * 256 + (size_t)((lchunk ^ lrow8) * 8));
    unsigned short* lwave = (isB ? Bs : As) + Rwave * 64;

    // ---- compute role: quadrant
    const int mq = (wave >> 1) * 64;
    const int nq = (wave & 1) * 64;
    const int lrow = lane & 15;
    const int kseg = lane >> 4;
    const int sw = lrow & 7;

    float4v acc[4][4];
    #pragma unroll
    for (int i = 0; i < 4; ++i)
        #pragma unroll
        for (int j = 0; j < 4; ++j)
            acc[i][j] = (float4v){0.f, 0.f, 0.f, 0.f};

    for (int s = 0; s < 12; ++s) {
        const int phase = s >> 2;
        const int sk = (s & 3) * 64;
        size_t srcOff = (size_t)sk;
        if (!isB) { if (phase == 1) srcOff += APROD; }   // Al in phase 1
        else      { if (phase == 2) srcOff += BPROD; }   // Bl in phase 2
        const unsigned short* g = sbase + srcOff;
        __syncthreads();   // previous step's compute done before overwrite
        #pragma unroll
        for (int q = 0; q < 8; ++q)
            gload_lds16(g + q * 2048, lwave + q * 512);
        __syncthreads();   // staging complete (vmcnt drain + barrier)
        #pragma unroll
        for (int t = 0; t < 2; ++t) {
            const int wch = ((t * 4 + kseg) ^ sw) * 8;
            short8 a[4], b[4];
            #pragma unroll
            for (int i = 0; i < 4; ++i)
                a[i] = *(const short8*)&As[(mq + i * 16 + lrow) * 64 + wch];
            #pragma unroll
            for (int j = 0; j < 4; ++j)
                b[j] = *(const short8*)&Bs[(nq + j * 16 + lrow) * 64 + wch];
            #pragma unroll
            for (int i = 0; i < 4; ++i)
                #pragma unroll
                for (int j = 0; j < 4; ++j)
                    acc[i][j] = __builtin_amdgcn_mfma_f32_16x16x32_bf16(
                        a[i], b[j], acc[i][j], 0, 0, 0);
        }
    }

    // ---- epilogue: score = q2[m] - 2*dot + xn2[t]; packed argmin ----
    float xnv[4];
    #pragma unroll
    for (int j = 0; j < 4; ++j)
        xnv[j] = xn2[ntile + nq + j * 16 + lrow];   // pads hold 3e38

    #pragma unroll
    for (int i = 0; i < 4; ++i) {
        #pragma unroll
        for (int r = 0; r < 4; ++r) {
            const int lm = mq + i * 16 + kseg * 4 + r;   // block-local query
            const int mi = mtile + lm;
            unsigned long long best = ~0ULL;
            if (mi < B) {
                float q2v = q2[mi];
                #pragma unroll
                for (int j = 0; j < 4; ++j) {
                    int t_ = ntile + nq + j * 16 + lrow;
                    float sc = fmaxf(q2v - 2.0f * acc[i][j][r] + xnv[j], 0.0f);
                    unsigned long long key =
                        ((unsigned long long)__float_as_uint(sc) << 32) | (unsigned int)t_;
                    best = (key < best) ? key : best;
                }
            }
            #pragma unroll
            for (int sft = 1; sft < 16; sft <<= 1) {
                unsigned long long o = __shfl_xor(best, sft);
                best = (o < best) ? o : best;
            }
            if (lrow == 0 && mi < B) atomicMin(&skey[lm], best);
        }
    }
    __syncthreads();
    if (tid < 128) {
        int mi = mtile + tid;
        if (mi < B && skey[tid] != ~0ULL) atomicMin(gkey + mi, skey[tid]);
    }
}

// One wave per query: 75 gathers across lanes, ballot bincount, bisect p-values.
__global__ void classify(const unsigned long long* __restrict__ gkey,
                         const int* __restrict__ labels,
                         const int* __restrict__ nbr,
                         const int* __restrict__ cali,
                         float* __restrict__ out,
                         int knm1, int nb_cali, int B)
{
    int q = blockIdx.x * 4 + (threadIdx.x >> 6);
    int lane = threadIdx.x & 63;
    if (q >= B) return;
    int closest = (int)(gkey[q] & 0xFFFFFFFFULL);
    int K = knm1 + 1;   // 75
    int lbl0 = -1, lbl1 = -1;
    if (lane < K) {
        int idx = (lane == 0) ? closest : nbr[(size_t)closest * knm1 + (lane - 1)];
        lbl0 = labels[idx];
    }
    int j2 = lane + 64;
    if (j2 < K) {
        int idx = nbr[(size_t)closest * knm1 + (j2 - 1)];
        lbl1 = labels[idx];
    }
    int bestc = 0, bestp = -1;
    #pragma unroll
    for (int c = 0; c < 10; ++c) {
        int cnt = __popcll(__ballot(lbl0 == c)) + __popcll(__ballot(lbl1 == c));
        int v = K - cnt;
        int lo = 0, hi = nb_cali;
        while (lo < hi) {                 // bisect_left
            int mid = (lo + hi) >> 1;
            if (cali[mid] < v) lo = mid + 1; else hi = mid;
        }
        int p = nb_cali - lo;
        if (p > bestp) { bestp = p; bestc = c; }   // strict > == first-occurrence argmax
    }
    float pv = (float)bestp / (float)nb_cali;
    if (lane < 10)
        out[(size_t)q * 10 + lane] = (lane == bestc) ? pv : 0.0f;
}

extern "C" void kernel_launch(void* const* d_in, const int* in_sizes, int n_in,
                              void* d_out, int out_size, void* d_ws, size_t ws_size,
                              hipStream_t stream) {
    const float* x      = (const float*)d_in[0];
    const float* X      = (const float*)d_in[1];
    const float* center = (const float*)d_in[2];
    const int* labels   = (const int*)d_in[3];
    const int* nbr      = (const int*)d_in[4];
    const int* cali     = (const int*)d_in[5];
    float* out = (float*)d_out;

    const int d        = in_sizes[2];              // 256
    const int B        = in_sizes[0] / d;          // 1024
    const int nb_train = in_sizes[3];              // 100000
    const int knm1     = in_sizes[4] / nb_train;   // 74
    const int nb_cali  = in_sizes[5];              // 1000

    const int Mp = (B + 127) & ~127;               // 1024
    const int Np = (nb_train + 127) & ~127;        // 100096

    char* ws = (char*)d_ws;
    size_t off = 0;
    unsigned long long* gkey = (unsigned long long*)(ws + off); off += (size_t)Mp * 8;
    unsigned short* Adata = (unsigned short*)(ws + off); off += (size_t)Mp * 256 * 2 * 2;
    float* q2 = (float*)(ws + off); off += (size_t)Mp * 4;
    unsigned short* Bdata = (unsigned short*)(ws + off); off += (size_t)Np * 256 * 2 * 2;
    float* xn2 = (float*)(ws + off); off += (size_t)Np * 4;

    unsigned short* Ah = Adata;
    unsigned short* Al = Adata + (size_t)Mp * 256;
    unsigned short* Bh = Bdata;
    unsigned short* Bl = Bdata + (size_t)Np * 256;

    const int train_blocks = 1024;
    prep_all<<<train_blocks + Mp, 256, 0, stream>>>(X, x, center, Bh, Bl, xn2,
                                                    Ah, Al, q2, gkey,
                                                    nb_train, Np, B, Mp, train_blocks);
    const int ntiles = Np / 128;                   // 782
    const int mtiles = Mp / 128;                   // 8
    const int nper   = (ntiles + 7) / 8;           // 98
    mfma_tile<<<8 * nper * mtiles, 256, 0, stream>>>(
        Adata, Bdata, q2, xn2, gkey, Mp, Np, nb_train, B, ntiles, nper, mtiles);
    classify<<<(B + 3) / 4, 256, 0, stream>>>(gkey, labels, nbr, cali, out,
                                              knm1, nb_cali, B);
}